// Round 1
// baseline (4540.168 us; speedup 1.0000x reference)
//
#include <hip/hip_runtime.h>
#include <hip/hip_bf16.h>

// Problem constants (fixed by the reference)
#define BSZ  64
#define ILEN 256
#define TLEN 64
#define TTOT (ILEN + TLEN)   // 320
#define IDIM 512
#define HDIM 1024
#define ODIM 128

// LSTM persistent-kernel config: 128 blocks x 512 threads (8 waves).
// Block owns 8 hidden units -> 32 gate rows (8 each of i,f,g,o).
// Waves split K (1536 = 512 ih + 1024 hh) 8 ways; weight bf16 fragments
// stay RESIDENT IN REGISTERS across all 320 timesteps (48 VGPR/wave).
#define NBLK 128
#define NTHR 512
#define UPB  8
#define PPITCH 68            // LDS partial pitch (floats): 16B-aligned, spreads banks

typedef __attribute__((ext_vector_type(8))) short short8;  // 8 x bf16
typedef __attribute__((ext_vector_type(4))) float f32x4;

__device__ inline ushort f2bf(float f) {            // RNE float->bf16
  unsigned u = __builtin_bit_cast(unsigned, f);
  u += 0x7fffu + ((u >> 16) & 1u);
  return (ushort)(u >> 16);
}

__device__ inline float fast_sigmoid(float x) {
  float e = __expf(-x);
  return 1.0f / (1.0f + e);
}
__device__ inline float fast_tanh(float x) {
  // tanh(x) = 1 - 2/(exp(2x)+1); saturates cleanly at +-1 for |x| large
  float e = __expf(2.0f * x);
  return 1.0f - 2.0f / (1.0f + e);
}

__device__ inline short8 pack8(const float* __restrict__ s) {
  const float4* p = (const float4*)s;
  float4 f0 = p[0], f1 = p[1];
  short8 r;
  r[0] = (short)f2bf(f0.x); r[1] = (short)f2bf(f0.y);
  r[2] = (short)f2bf(f0.z); r[3] = (short)f2bf(f0.w);
  r[4] = (short)f2bf(f1.x); r[5] = (short)f2bf(f1.y);
  r[6] = (short)f2bf(f1.z); r[7] = (short)f2bf(f1.w);
  return r;
}

// ---------------- prep: fp32->bf16 conversions, zero h0, zero barrier ----------------
__global__ void prep_kernel(const float* __restrict__ inp, const float* __restrict__ clfw,
                            ushort* __restrict__ inp_bf, ushort* __restrict__ clfw_bf,
                            ushort* __restrict__ hbuf, int* __restrict__ bar)
{
  const long np  = (long)gridDim.x * blockDim.x;
  const long tid = (long)blockIdx.x * blockDim.x + threadIdx.x;

  const float4* in4 = (const float4*)inp;
  ushort4* ob4 = (ushort4*)inp_bf;
  for (long i = tid; i < (long)BSZ * ILEN * IDIM / 4; i += np) {
    float4 v = in4[i];
    ushort4 o; o.x = f2bf(v.x); o.y = f2bf(v.y); o.z = f2bf(v.z); o.w = f2bf(v.w);
    ob4[i] = o;
  }
  const float4* cw4 = (const float4*)clfw;
  ushort4* cb4 = (ushort4*)clfw_bf;
  for (long i = tid; i < (long)ODIM * HDIM / 4; i += np) {
    float4 v = cw4[i];
    ushort4 o; o.x = f2bf(v.x); o.y = f2bf(v.y); o.z = f2bf(v.z); o.w = f2bf(v.w);
    cb4[i] = o;
  }
  ushort4 z; z.x = z.y = z.z = z.w = 0;
  ushort4* hb4 = (ushort4*)hbuf;
  for (long i = tid; i < (long)2 * BSZ * HDIM / 4; i += np) hb4[i] = z;
  if (tid < 512) bar[tid] = 0;   // barrier state re-zeroed every launch (ws is poisoned)
}

// ---------------- hierarchical device-scope grid barrier ----------------
#define LEAFS 8
#define BLK_PER_LEAF (NBLK / LEAFS)

__device__ inline void gridbar(int* __restrict__ bar, int tid, int blk) {
  __syncthreads();                      // drains vmcnt: h stores done before release
  if (tid == 0) {
    int* genp = bar + 288;
    const int gen = __hip_atomic_load(genp, __ATOMIC_ACQUIRE, __HIP_MEMORY_SCOPE_AGENT);
    int* leafp = bar + 32 * (blk & (LEAFS - 1));     // separate cache lines
    const int lo = __hip_atomic_fetch_add(leafp, 1, __ATOMIC_ACQ_REL, __HIP_MEMORY_SCOPE_AGENT);
    bool done = false;
    if (lo == BLK_PER_LEAF - 1) {
      __hip_atomic_store(leafp, 0, __ATOMIC_RELAXED, __HIP_MEMORY_SCOPE_AGENT);
      int* rootp = bar + 256;
      const int ro = __hip_atomic_fetch_add(rootp, 1, __ATOMIC_ACQ_REL, __HIP_MEMORY_SCOPE_AGENT);
      if (ro == LEAFS - 1) {
        __hip_atomic_store(rootp, 0, __ATOMIC_RELAXED, __HIP_MEMORY_SCOPE_AGENT);
        __hip_atomic_store(genp, gen + 1, __ATOMIC_RELEASE, __HIP_MEMORY_SCOPE_AGENT);
        done = true;
      }
    }
    if (!done) {
      while (__hip_atomic_load(genp, __ATOMIC_RELAXED, __HIP_MEMORY_SCOPE_AGENT) == gen)
        __builtin_amdgcn_s_sleep(2);
      __threadfence();                  // acquire: invalidates L1/L2 for fresh h reads
    }
  }
  __syncthreads();
}

// ---------------- persistent LSTM kernel ----------------
// MFMA 16x16x32 bf16 layouts (guide, m89/m91/m120 verified):
//   A frag: A[m = lane&15][k = (lane>>4)*8 + j]
//   B frag: B-col n = lane&15, k = (lane>>4)*8 + j  (we feed W[n][k] rows)
//   C/D:    col(n) = lane&15, row(m) = (lane>>4)*4 + reg
#define MFMA8(a, ci) do {                                                              \
  _Pragma("unroll")                                                                    \
  for (int _mt = 0; _mt < 4; ++_mt) {                                                  \
    acc[_mt][0] = __builtin_amdgcn_mfma_f32_16x16x32_bf16(a[_mt], wfrag[ci][0], acc[_mt][0], 0, 0, 0); \
    acc[_mt][1] = __builtin_amdgcn_mfma_f32_16x16x32_bf16(a[_mt], wfrag[ci][1], acc[_mt][1], 0, 0, 0); \
  }                                                                                    \
} while (0)

#define LOAD4(dst, baseptr, rstride) do {                                              \
  _Pragma("unroll")                                                                    \
  for (int _mt = 0; _mt < 4; ++_mt)                                                    \
    dst[_mt] = *(const short8*)((baseptr) + (long)(_mt * 16 + l15) * (rstride));       \
} while (0)

__global__ __launch_bounds__(NTHR, 1) void lstm_kernel(
    const ushort* __restrict__ inp_bf,
    const float* __restrict__ w_ih, const float* __restrict__ w_hh,
    const float* __restrict__ bias,
    ushort* __restrict__ hbuf, ushort* __restrict__ hs_bf,
    int* __restrict__ bar)
{
  extern __shared__ float part[];   // [8 waves][32 n][PPITCH] partial gates

  const int tid  = threadIdx.x;
  const int wv   = tid >> 6;        // wave 0..7
  const int lane = tid & 63;
  const int l15  = lane & 15;
  const int quad = lane >> 4;
  const int blk  = blockIdx.x;
  const int j0   = blk * UPB;       // first hidden unit owned by this block

  // ---- load this block's 32 gate rows as register-resident bf16 fragments ----
  // K owned by wave wv: ih chunks c = wv, wv+8 ; hh chunks c = 16+wv+8*{0..3}
  short8 wfrag[6][2];
  #pragma unroll
  for (int nt = 0; nt < 2; ++nt) {
    const int nl = nt * 16 + l15;                       // 0..31: gate = nl>>3, unit = nl&7
    const long grow = (long)(nl >> 3) * HDIM + j0 + (nl & 7);
    #pragma unroll
    for (int ci = 0; ci < 2; ++ci) {
      const int k = (wv + 8 * ci) * 32 + quad * 8;      // [0,512)
      wfrag[ci][nt] = pack8(w_ih + grow * IDIM + k);
    }
    #pragma unroll
    for (int ci = 2; ci < 6; ++ci) {
      const int k = wv * 32 + (ci - 2) * 256 + quad * 8; // [0,1024)
      wfrag[ci][nt] = pack8(w_hh + grow * HDIM + k);
    }
  }

  // ---- elementwise state: thread owns (batch em, unit u) ----
  const int em = tid & 63;
  const int u  = tid >> 6;          // 0..7
  const float bi = bias[0 * HDIM + j0 + u];
  const float bf_ = bias[1 * HDIM + j0 + u];
  const float bg = bias[2 * HDIM + j0 + u];
  const float bo = bias[3 * HDIM + j0 + u];
  float cst = 0.0f;

  for (int t = 0; t < TTOT; ++t) {
    const int p = t & 1;
    const ushort* __restrict__ hsrc = hbuf + p * (BSZ * HDIM);
    ushort* __restrict__ hdst = hbuf + (p ^ 1) * (BSZ * HDIM);

    f32x4 acc[4][2];
    #pragma unroll
    for (int mt = 0; mt < 4; ++mt)
      #pragma unroll
      for (int nt = 0; nt < 2; ++nt)
        #pragma unroll
        for (int r = 0; r < 4; ++r) acc[mt][nt][r] = 0.0f;

    short8 aA[4], aB[4];
    const ushort* hb = hsrc + wv * 32 + quad * 8;

    if (t < ILEN) {   // fused input projection: K = 512(ih) + 1024(hh)
      const ushort* xb = inp_bf + (long)t * IDIM + wv * 32 + quad * 8;
      LOAD4(aA, xb, (long)ILEN * IDIM);
      LOAD4(aB, xb + 256, (long)ILEN * IDIM);
      MFMA8(aA, 0);
      LOAD4(aA, hb, HDIM);
      MFMA8(aB, 1);
      LOAD4(aB, hb + 256, HDIM);
      MFMA8(aA, 2);
      LOAD4(aA, hb + 512, HDIM);
      MFMA8(aB, 3);
      LOAD4(aB, hb + 768, HDIM);
      MFMA8(aA, 4);
      MFMA8(aB, 5);
    } else {          // padded steps: x contribution is just the bias
      LOAD4(aA, hb, HDIM);
      LOAD4(aB, hb + 256, HDIM);
      MFMA8(aA, 2);
      LOAD4(aA, hb + 512, HDIM);
      MFMA8(aB, 3);
      LOAD4(aB, hb + 768, HDIM);
      MFMA8(aA, 4);
      MFMA8(aB, 5);
    }

    // ---- write per-wave partial gates to LDS (b128, [w][n][m] layout) ----
    #pragma unroll
    for (int mt = 0; mt < 4; ++mt)
      #pragma unroll
      for (int nt = 0; nt < 2; ++nt) {
        float* dst = &part[(wv * 32 + nt * 16 + l15) * PPITCH + mt * 16 + quad * 4];
        *(f32x4*)dst = acc[mt][nt];
      }
    __syncthreads();

    // ---- reduce 8 wave-partials, apply LSTM cell ----
    float gi = bi, gf = bf_, gg = bg, go = bo;
    #pragma unroll
    for (int w = 0; w < 8; ++w) {
      const float* pw = part + (w * 32) * PPITCH;
      gi += pw[(0 * 8 + u) * PPITCH + em];
      gf += pw[(1 * 8 + u) * PPITCH + em];
      gg += pw[(2 * 8 + u) * PPITCH + em];
      go += pw[(3 * 8 + u) * PPITCH + em];
    }
    const float si = fast_sigmoid(gi);
    const float sf = fast_sigmoid(gf);
    const float tg = fast_tanh(gg);
    const float so = fast_sigmoid(go);
    cst = sf * cst + si * tg;
    const float h = so * fast_tanh(cst);
    const ushort hb16 = f2bf(h);
    hdst[em * HDIM + j0 + u] = hb16;
    if (t >= ILEN)
      hs_bf[((long)em * TLEN + (t - ILEN)) * HDIM + j0 + u] = hb16;

    gridbar(bar, tid, blk);   // one barrier per step (double-buffered h)
  }
}

// ---------------- classifier: sigmoid(hs @ clf_w^T + clf_b) ----------------
__global__ __launch_bounds__(256, 1) void clf_kernel(
    const ushort* __restrict__ hs_bf, const ushort* __restrict__ clfw_bf,
    const float* __restrict__ clf_b, float* __restrict__ out)
{
  const int tid = threadIdx.x;
  const int wv = tid >> 6, lane = tid & 63, l15 = lane & 15, quad = lane >> 4;
  const int m0 = blockIdx.x * 64 + wv * 16;   // rows = (b, tt) pairs, 4096 total

  f32x4 acc[8];
  #pragma unroll
  for (int nt = 0; nt < 8; ++nt)
    #pragma unroll
    for (int r = 0; r < 4; ++r) acc[nt][r] = 0.0f;

  for (int kc = 0; kc < HDIM / 32; ++kc) {
    const int k = kc * 32 + quad * 8;
    short8 a = *(const short8*)(hs_bf + (long)(m0 + l15) * HDIM + k);
    #pragma unroll
    for (int nt = 0; nt < 8; ++nt) {
      short8 b = *(const short8*)(clfw_bf + (long)(nt * 16 + l15) * HDIM + k);
      acc[nt] = __builtin_amdgcn_mfma_f32_16x16x32_bf16(a, b, acc[nt], 0, 0, 0);
    }
  }
  #pragma unroll
  for (int nt = 0; nt < 8; ++nt) {
    const int n = nt * 16 + l15;
    const float bn = clf_b[n];
    #pragma unroll
    for (int r = 0; r < 4; ++r) {
      const int m = m0 + quad * 4 + r;
      out[(long)m * ODIM + n] = fast_sigmoid(acc[nt][r] + bn);
    }
  }
}

// ---------------- launch ----------------
extern "C" void kernel_launch(void* const* d_in, const int* in_sizes, int n_in,
                              void* d_out, int out_size, void* d_ws, size_t ws_size,
                              hipStream_t stream) {
  const float* inp   = (const float*)d_in[0];
  // d_in[1] = tlen scalar (fixed = 64 for this problem)
  const float* w_ih  = (const float*)d_in[2];
  const float* w_hh  = (const float*)d_in[3];
  const float* bias  = (const float*)d_in[4];
  const float* clf_w = (const float*)d_in[5];
  const float* clf_b = (const float*)d_in[6];
  float* out = (float*)d_out;

  // ws layout (bytes): total ~24.5 MB
  char* ws = (char*)d_ws;
  ushort* inp_bf  = (ushort*)(ws + 0);          // 16,777,216
  ushort* clfw_bf = (ushort*)(ws + 16777216);   //    262,144
  ushort* hbuf    = (ushort*)(ws + 17039360);   //    262,144 (double-buffered h, bf16)
  ushort* hs_bf   = (ushort*)(ws + 17301504);   //  8,388,608 (last-64-step h history)
  int*    bar     = (int*)   (ws + 25690112);   //      2,048 (barrier state)

  prep_kernel<<<2048, 256, 0, stream>>>(inp, clf_w, inp_bf, clfw_bf, hbuf, bar);
  lstm_kernel<<<NBLK, NTHR, 8 * 32 * PPITCH * 4, stream>>>(inp_bf, w_ih, w_hh, bias,
                                                           hbuf, hs_bf, bar);
  clf_kernel<<<64, 256, 0, stream>>>(hs_bf, clfw_bf, clf_b, out);
}

// Round 2
// 4088.693 us; speedup vs baseline: 1.1104x; 1.1104x over previous
//
#include <hip/hip_runtime.h>
#include <hip/hip_bf16.h>

// Problem constants (fixed by the reference)
#define BSZ  64
#define ILEN 256
#define TLEN 64
#define TTOT (ILEN + TLEN)   // 320
#define IDIM 512
#define HDIM 1024
#define ODIM 128

// Partition: 4 batch-groups x 16 rows. Each group = 32 blocks; block owns
// 32 hidden units -> 128 gate rows (32 each of i,f,g,o), full K=1536 resident
// in registers as bf16 MFMA fragments (8 n-tiles x 6 K-chunks x 8 = 192 VGPR).
// Barrier is per-group (32 flags, decentralized store+poll), NOT global.
#define NBLK 128
#define NTHR 512
#define GRP  4           // batch groups
#define GBLK 32          // blocks per group
#define NT   8           // n-tiles (16 each) per block = 128 gate rows
#define NCH  6           // K-chunks of 32 per wave (2 ih + 4 hh)
#define PP   20          // LDS partial pitch in floats (16B aligned, bank-spread)

typedef __attribute__((ext_vector_type(8))) short short8;  // 8 x bf16
typedef __attribute__((ext_vector_type(4))) float f32x4;

__device__ inline ushort f2bf(float f) {            // RNE float->bf16
  unsigned u = __builtin_bit_cast(unsigned, f);
  u += 0x7fffu + ((u >> 16) & 1u);
  return (ushort)(u >> 16);
}

__device__ inline float fast_sigmoid(float x) {
  float e = __expf(-x);
  return 1.0f / (1.0f + e);
}
__device__ inline float fast_tanh(float x) {
  float e = __expf(2.0f * x);
  return 1.0f - 2.0f / (1.0f + e);
}

__device__ inline short8 pack8(const float* __restrict__ s) {
  const float4* p = (const float4*)s;
  float4 f0 = p[0], f1 = p[1];
  short8 r;
  r[0] = (short)f2bf(f0.x); r[1] = (short)f2bf(f0.y);
  r[2] = (short)f2bf(f0.z); r[3] = (short)f2bf(f0.w);
  r[4] = (short)f2bf(f1.x); r[5] = (short)f2bf(f1.y);
  r[6] = (short)f2bf(f1.z); r[7] = (short)f2bf(f1.w);
  return r;
}

// ---------------- prep: fp32->bf16 conversions, zero h0, zero flags ----------------
__global__ void prep_kernel(const float* __restrict__ inp, const float* __restrict__ clfw,
                            ushort* __restrict__ inp_bf, ushort* __restrict__ clfw_bf,
                            ushort* __restrict__ hbuf, int* __restrict__ bar)
{
  const long np  = (long)gridDim.x * blockDim.x;
  const long tid = (long)blockIdx.x * blockDim.x + threadIdx.x;

  const float4* in4 = (const float4*)inp;
  ushort4* ob4 = (ushort4*)inp_bf;
  for (long i = tid; i < (long)BSZ * ILEN * IDIM / 4; i += np) {
    float4 v = in4[i];
    ushort4 o; o.x = f2bf(v.x); o.y = f2bf(v.y); o.z = f2bf(v.z); o.w = f2bf(v.w);
    ob4[i] = o;
  }
  const float4* cw4 = (const float4*)clfw;
  ushort4* cb4 = (ushort4*)clfw_bf;
  for (long i = tid; i < (long)ODIM * HDIM / 4; i += np) {
    float4 v = cw4[i];
    ushort4 o; o.x = f2bf(v.x); o.y = f2bf(v.y); o.z = f2bf(v.z); o.w = f2bf(v.w);
    cb4[i] = o;
  }
  ushort4 z; z.x = z.y = z.z = z.w = 0;
  ushort4* hb4 = (ushort4*)hbuf;
  for (long i = tid; i < (long)2 * BSZ * HDIM / 4; i += np) hb4[i] = z;
  if (tid < 8192) bar[tid] = 0;   // flags re-zeroed every launch (ws is poisoned)
}

// ---------------- persistent LSTM kernel ----------------
// MFMA 16x16x32 bf16 layouts (validated round 1):
//   A frag: A[m = lane&15][k = (lane>>4)*8 + j]
//   B frag: rows W[n][k], n = lane&15, k = (lane>>4)*8 + j
//   C/D:    col(n) = lane&15, row(m) = (lane>>4)*4 + reg
__global__ __launch_bounds__(NTHR, 2) void lstm_kernel(
    const ushort* __restrict__ inp_bf,
    const float* __restrict__ w_ih, const float* __restrict__ w_hh,
    const float* __restrict__ bias,
    ushort* __restrict__ hbuf, ushort* __restrict__ hs_bf,
    int* __restrict__ flags)
{
  extern __shared__ float part[];   // [8 waves][128 n][PP] partial gates (80 KB)

  const int tid  = threadIdx.x;
  const int wv   = tid >> 6;        // wave 0..7 (K split 8 ways)
  const int lane = tid & 63;
  const int l15  = lane & 15;
  const int quad = lane >> 4;
  const int blk  = blockIdx.x;
  const int g    = blk >> 5;        // batch group 0..3
  const int gb   = blk & 31;        // block within group
  const int j0u  = gb * 32;         // first hidden unit owned by this block
  const int m0   = g * 16;          // first batch row of this group

  // ---- register-resident bf16 weight fragments: 128 gate rows x K slice ----
  short8 wfrag[NCH][NT];
  #pragma unroll
  for (int nt = 0; nt < NT; ++nt) {
    const int nl = nt * 16 + l15;                       // 0..127
    const long grow = (long)(nl >> 5) * HDIM + j0u + (nl & 31);
    #pragma unroll
    for (int ci = 0; ci < 2; ++ci) {                    // ih: K in [0,512)
      const int k = (wv + 8 * ci) * 32 + quad * 8;
      wfrag[ci][nt] = pack8(w_ih + grow * IDIM + k);
    }
    #pragma unroll
    for (int ci = 2; ci < 6; ++ci) {                    // hh: K in [0,1024)
      const int k = wv * 32 + (ci - 2) * 256 + quad * 8;
      wfrag[ci][nt] = pack8(w_hh + grow * HDIM + k);
    }
  }

  // ---- elementwise cell mapping: thread <-> (batch em, unit uu) coalesced in uu ----
  const int em = tid >> 5;          // 0..15 batch row within group
  const int uu = tid & 31;          // 0..31 unit within block's slice
  const float bi  = bias[0 * HDIM + j0u + uu];
  const float bf_ = bias[1 * HDIM + j0u + uu];
  const float bg  = bias[2 * HDIM + j0u + uu];
  const float bo  = bias[3 * HDIM + j0u + uu];
  float cst = 0.0f;

  int* const fbase = flags + g * GBLK * 32;   // this group's flag array
  int* const fmine = flags + blk * 32;        // own flag (128B stride)

  // prefetch x fragments for t=0
  short8 xa0, xa1;
  {
    const ushort* xb = inp_bf + (long)(m0 + l15) * ILEN * IDIM;  // t=0
    xa0 = *(const short8*)(xb + wv * 32 + quad * 8);
    xa1 = *(const short8*)(xb + (wv + 8) * 32 + quad * 8);
  }

  for (int t = 0; t < TTOT; ++t) {
    const int p = t & 1;
    const ushort* __restrict__ hsrc = hbuf + p * (BSZ * HDIM);
    ushort* __restrict__ hdst = hbuf + (p ^ 1) * (BSZ * HDIM);

    // ---- gate GEMM: acc[n-tile] over this wave's K slice ----
    f32x4 acc[NT];
    #pragma unroll
    for (int nt = 0; nt < NT; ++nt)
      #pragma unroll
      for (int r = 0; r < 4; ++r) acc[nt][r] = 0.0f;

    const ushort* hb = hsrc + (long)(m0 + l15) * HDIM;
    short8 ah[4];
    #pragma unroll
    for (int c = 0; c < 4; ++c)
      ah[c] = *(const short8*)(hb + wv * 32 + c * 256 + quad * 8);

    if (t < ILEN) {
      #pragma unroll
      for (int nt = 0; nt < NT; ++nt)
        acc[nt] = __builtin_amdgcn_mfma_f32_16x16x32_bf16(xa0, wfrag[0][nt], acc[nt], 0, 0, 0);
      #pragma unroll
      for (int nt = 0; nt < NT; ++nt)
        acc[nt] = __builtin_amdgcn_mfma_f32_16x16x32_bf16(xa1, wfrag[1][nt], acc[nt], 0, 0, 0);
    }
    #pragma unroll
    for (int c = 0; c < 4; ++c)
      #pragma unroll
      for (int nt = 0; nt < NT; ++nt)
        acc[nt] = __builtin_amdgcn_mfma_f32_16x16x32_bf16(ah[c], wfrag[2 + c][nt], acc[nt], 0, 0, 0);

    // ---- per-wave partials to LDS ----
    #pragma unroll
    for (int nt = 0; nt < NT; ++nt) {
      float* dst = &part[(wv * 128 + nt * 16 + l15) * PP + quad * 4];
      *(f32x4*)dst = acc[nt];
    }
    __syncthreads();

    // ---- reduce 8 partials, LSTM cell ----
    float gi = bi, gf = bf_, gg = bg, go = bo;
    #pragma unroll
    for (int w = 0; w < 8; ++w) {
      const float* pw = part + w * 128 * PP;
      gi += pw[(0 * 32 + uu) * PP + em];
      gf += pw[(1 * 32 + uu) * PP + em];
      gg += pw[(2 * 32 + uu) * PP + em];
      go += pw[(3 * 32 + uu) * PP + em];
    }
    const float si = fast_sigmoid(gi);
    const float sf = fast_sigmoid(gf);
    const float tg = fast_tanh(gg);
    const float so = fast_sigmoid(go);
    cst = sf * cst + si * tg;
    const float h = so * fast_tanh(cst);
    const ushort h16 = f2bf(h);
    hdst[(long)(m0 + em) * HDIM + j0u + uu] = h16;          // 64B runs, coalesced
    if (t >= ILEN)
      hs_bf[((long)(m0 + em) * TLEN + (t - ILEN)) * HDIM + j0u + uu] = h16;

    // ---- prefetch x for t+1 (independent of barrier) ----
    if (t + 1 < ILEN) {
      const ushort* xb = inp_bf + ((long)(m0 + l15) * ILEN + (t + 1)) * IDIM;
      xa0 = *(const short8*)(xb + wv * 32 + quad * 8);
      xa1 = *(const short8*)(xb + (wv + 8) * 32 + quad * 8);
    }

    // ---- decentralized per-group barrier ----
    __syncthreads();                         // drains vmcnt: h stores issued
    if (tid == 0) {
      __threadfence();                       // L2 writeback (cross-XCD visibility)
      __hip_atomic_store(fmine, t + 1, __ATOMIC_RELEASE, __HIP_MEMORY_SCOPE_AGENT);
    }
    if (wv == 0) {
      for (;;) {
        int v = (lane < GBLK)
          ? __hip_atomic_load(fbase + lane * 32, __ATOMIC_RELAXED, __HIP_MEMORY_SCOPE_AGENT)
          : 0x7fffffff;
        if (__all(v > t)) break;
        __builtin_amdgcn_s_sleep(1);
      }
      if (lane == 0) __threadfence();        // acquire: invalidate L1/L2 before h reads
    }
    __syncthreads();
  }
}

// ---------------- classifier: sigmoid(hs @ clf_w^T + clf_b) ----------------
__global__ __launch_bounds__(256, 1) void clf_kernel(
    const ushort* __restrict__ hs_bf, const ushort* __restrict__ clfw_bf,
    const float* __restrict__ clf_b, float* __restrict__ out)
{
  const int tid = threadIdx.x;
  const int wv = tid >> 6, lane = tid & 63, l15 = lane & 15, quad = lane >> 4;
  const int m0 = blockIdx.x * 64 + wv * 16;   // rows = (b, tt) pairs, 4096 total

  f32x4 acc[8];
  #pragma unroll
  for (int nt = 0; nt < 8; ++nt)
    #pragma unroll
    for (int r = 0; r < 4; ++r) acc[nt][r] = 0.0f;

  for (int kc = 0; kc < HDIM / 32; ++kc) {
    const int k = kc * 32 + quad * 8;
    short8 a = *(const short8*)(hs_bf + (long)(m0 + l15) * HDIM + k);
    #pragma unroll
    for (int nt = 0; nt < 8; ++nt) {
      short8 b = *(const short8*)(clfw_bf + (long)(nt * 16 + l15) * HDIM + k);
      acc[nt] = __builtin_amdgcn_mfma_f32_16x16x32_bf16(a, b, acc[nt], 0, 0, 0);
    }
  }
  #pragma unroll
  for (int nt = 0; nt < 8; ++nt) {
    const int n = nt * 16 + l15;
    const float bn = clf_b[n];
    #pragma unroll
    for (int r = 0; r < 4; ++r) {
      const int m = m0 + quad * 4 + r;
      out[(long)m * ODIM + n] = fast_sigmoid(acc[nt][r] + bn);
    }
  }
}

// ---------------- launch ----------------
extern "C" void kernel_launch(void* const* d_in, const int* in_sizes, int n_in,
                              void* d_out, int out_size, void* d_ws, size_t ws_size,
                              hipStream_t stream) {
  const float* inp   = (const float*)d_in[0];
  // d_in[1] = tlen scalar (fixed = 64 for this problem)
  const float* w_ih  = (const float*)d_in[2];
  const float* w_hh  = (const float*)d_in[3];
  const float* bias  = (const float*)d_in[4];
  const float* clf_w = (const float*)d_in[5];
  const float* clf_b = (const float*)d_in[6];
  float* out = (float*)d_out;

  // ws layout (bytes): total ~25.72 MB
  char* ws = (char*)d_ws;
  ushort* inp_bf  = (ushort*)(ws + 0);          // 16,777,216
  ushort* clfw_bf = (ushort*)(ws + 16777216);   //    262,144
  ushort* hbuf    = (ushort*)(ws + 17039360);   //    262,144 (double-buffered h, bf16)
  ushort* hs_bf   = (ushort*)(ws + 17301504);   //  8,388,608 (last-64-step h history)
  int*    bar     = (int*)   (ws + 25690112);   //     32,768 (per-block flags)

  prep_kernel<<<2048, 256, 0, stream>>>(inp, clf_w, inp_bf, clfw_bf, hbuf, bar);
  lstm_kernel<<<NBLK, NTHR, 8 * 128 * PP * 4, stream>>>(inp_bf, w_ih, w_hh, bias,
                                                        hbuf, hs_bf, bar);
  clf_kernel<<<64, 256, 0, stream>>>(hs_bf, clfw_bf, clf_b, out);
}

// Round 4
// 1525.061 us; speedup vs baseline: 2.9770x; 2.6810x over previous
//
#include <hip/hip_runtime.h>
#include <hip/hip_bf16.h>

// Problem constants (fixed by the reference)
#define BSZ  64
#define ILEN 256
#define TLEN 64
#define TTOT (ILEN + TLEN)   // 320
#define IDIM 512
#define HDIM 1024
#define ODIM 128

// Partition: 4 batch-groups x 16 rows; 64 blocks/group (256 blocks = all CUs).
// Block owns 16 hidden units -> 64 gate rows (NT=4 n-tiles), K=1536 split over
// 8 waves; weight frags pre-swizzled bf16, register-resident (96 VGPR/wave).
// Cross-block h/flag traffic: __hip_atomic relaxed SYSTEM scope = sc0 sc1
// L1/L2-bypass to memory-side Infinity Cache (coherent, fence-free, and the
// compiler tracks the waitcnts -- round 3's asm loads raced their own waits).
#define NBLK 256
#define NTHR 512
#define GRP  4
#define GBLK 64          // blocks per group
#define UPB  16          // hidden units per block
#define NT   4           // n-tiles (16 gate rows each)
#define PQ   76          // LDS partial pitch (floats)

typedef __attribute__((ext_vector_type(8))) short short8;  // 8 x bf16
typedef __attribute__((ext_vector_type(4))) float f32x4;

__device__ inline ushort f2bf(float f) {            // RNE float->bf16
  unsigned u = __builtin_bit_cast(unsigned, f);
  u += 0x7fffu + ((u >> 16) & 1u);
  return (ushort)(u >> 16);
}

__device__ inline float fast_sigmoid(float x) {
  float e = __expf(-x);
  return 1.0f / (1.0f + e);
}
__device__ inline float fast_tanh(float x) {
  float e = __expf(2.0f * x);
  return 1.0f - 2.0f / (1.0f + e);
}

// ---- IF-coherent ops (compiler-known: waitcnts auto-inserted) ----
__device__ inline short8 ld_h16(const ushort* p) {   // 16B via 2x8B system loads
  unsigned long lo = __hip_atomic_load((const unsigned long*)p,
                                       __ATOMIC_RELAXED, __HIP_MEMORY_SCOPE_SYSTEM);
  unsigned long hi = __hip_atomic_load((const unsigned long*)(p + 4),
                                       __ATOMIC_RELAXED, __HIP_MEMORY_SCOPE_SYSTEM);
  union { unsigned long u[2]; short8 v; } c;
  c.u[0] = lo; c.u[1] = hi;
  return c.v;
}
__device__ inline void st_h(ushort* p, ushort v) {
  __hip_atomic_store(p, v, __ATOMIC_RELAXED, __HIP_MEMORY_SCOPE_SYSTEM);
}
__device__ inline int ld_flag(const int* p) {
  return __hip_atomic_load(p, __ATOMIC_RELAXED, __HIP_MEMORY_SCOPE_SYSTEM);
}
__device__ inline void st_flag(int* p, int v) {
  __hip_atomic_store(p, v, __ATOMIC_RELAXED, __HIP_MEMORY_SCOPE_SYSTEM);
}
__device__ inline void vm_drain() { asm volatile("s_waitcnt vmcnt(0)" ::: "memory"); }

// ---------------- prep: bf16 conversions, weight swizzle, zero h0/flags ----------------
// wsw fragment index f = (((gb*8 + wv)*6 + ci)*4 + nt)*64 + lane; 8 bf16 each.
__global__ void prep_kernel(const float* __restrict__ inp, const float* __restrict__ clfw,
                            const float* __restrict__ w_ih, const float* __restrict__ w_hh,
                            ushort* __restrict__ inp_bf, ushort* __restrict__ clfw_bf,
                            ushort* __restrict__ wsw,
                            ushort* __restrict__ hbuf, int* __restrict__ bar)
{
  const long np  = (long)gridDim.x * blockDim.x;
  const long tid = (long)blockIdx.x * blockDim.x + threadIdx.x;

  const float4* in4 = (const float4*)inp;
  ushort4* ob4 = (ushort4*)inp_bf;
  for (long i = tid; i < (long)BSZ * ILEN * IDIM / 4; i += np) {
    float4 v = in4[i];
    ushort4 o; o.x = f2bf(v.x); o.y = f2bf(v.y); o.z = f2bf(v.z); o.w = f2bf(v.w);
    ob4[i] = o;
  }
  const float4* cw4 = (const float4*)clfw;
  ushort4* cb4 = (ushort4*)clfw_bf;
  for (long i = tid; i < (long)ODIM * HDIM / 4; i += np) {
    float4 v = cw4[i];
    ushort4 o; o.x = f2bf(v.x); o.y = f2bf(v.y); o.z = f2bf(v.z); o.w = f2bf(v.w);
    cb4[i] = o;
  }
  // weight swizzle: 64gb x 8wv x 6ci x 4nt x 64lane fragments of 8
  for (long f = tid; f < 64L * 8 * 6 * 4 * 64; f += np) {
    const int lane = (int)(f & 63);
    const int nt   = (int)((f >> 6) & 3);
    const int ci   = (int)((f >> 8) % 6);
    const int gbwv = (int)(f / 1536);
    const int wv   = gbwv & 7;
    const int gb   = gbwv >> 3;
    const int l15  = lane & 15, quad = lane >> 4;
    const int nl   = nt * 16 + l15;
    const long grow = (long)(nl >> 4) * HDIM + gb * 16 + (nl & 15);
    const float* src;
    if (ci < 2) src = w_ih + grow * IDIM + (wv + 8 * ci) * 32 + quad * 8;
    else        src = w_hh + grow * HDIM + wv * 32 + (ci - 2) * 256 + quad * 8;
    ushort* dst = wsw + f * 8;
    #pragma unroll
    for (int j = 0; j < 8; ++j) dst[j] = f2bf(src[j]);
  }
  // zero h0 through the SAME (system/IF) path readers use
  for (long i = tid; i < (long)2 * BSZ * HDIM; i += np)
    st_h(hbuf + i, 0);
  for (long i = tid; i < NBLK * 32; i += np) st_flag(bar + (int)i, 0);
}

// ---------------- persistent LSTM kernel ----------------
// MFMA 16x16x32 bf16 layouts (validated rounds 1-2):
//   A frag: A[m = lane&15][k = (lane>>4)*8 + j]
//   B frag: rows W[n][k], n = lane&15, k = (lane>>4)*8 + j
//   C/D:    col(n) = lane&15, row(m) = (lane>>4)*4 + reg
__global__ __launch_bounds__(NTHR, 2) void lstm_kernel(
    const ushort* __restrict__ inp_bf, const ushort* __restrict__ wsw,
    const float* __restrict__ bias,
    ushort* __restrict__ hbuf, ushort* __restrict__ hs_bf,
    int* __restrict__ flags)
{
  extern __shared__ float part[];   // [8 waves][16 m][PQ]

  const int tid  = threadIdx.x;
  const int wv   = tid >> 6;        // wave 0..7 (K split 8 ways)
  const int lane = tid & 63;
  const int l15  = lane & 15;
  const int quad = lane >> 4;
  const int blk  = blockIdx.x;
  const int g    = blk >> 6;        // batch group 0..3
  const int gb   = blk & 63;        // block within group
  const int j0u  = gb * UPB;        // first hidden unit owned by this block
  const int m0   = g * 16;          // first batch row of this group

  // ---- register-resident pre-swizzled bf16 weight fragments ----
  short8 wfrag[6][NT];
  {
    const ushort* wp = wsw + ((long)(gb * 8 + wv) * 6 * 4 * 64 + lane) * 8;
    #pragma unroll
    for (int ci = 0; ci < 6; ++ci)
      #pragma unroll
      for (int nt = 0; nt < NT; ++nt)
        wfrag[ci][nt] = *(const short8*)(wp + (long)(ci * 4 + nt) * 64 * 8);
  }

  // ---- elementwise cell mapping: threads 0..255 own (batch em, unit uu) ----
  const int em = tid >> 4;          // 0..15 (valid when tid<256)
  const int uu = tid & 15;          // 0..15
  float bi = 0, bf_ = 0, bg = 0, bo = 0;
  if (tid < 256) {
    bi  = bias[0 * HDIM + j0u + uu];
    bf_ = bias[1 * HDIM + j0u + uu];
    bg  = bias[2 * HDIM + j0u + uu];
    bo  = bias[3 * HDIM + j0u + uu];
  }
  float cst = 0.0f;

  int* const fbase = flags + g * GBLK * 32;   // this group's 64 flags
  int* const fmine = flags + blk * 32;        // own flag (128B stride)

  // prefetch x fragments for t=0 (read-only, plain cached loads)
  short8 xa0, xa1;
  {
    const ushort* xb = inp_bf + (long)(m0 + l15) * ILEN * IDIM;
    xa0 = *(const short8*)(xb + wv * 32 + quad * 8);
    xa1 = *(const short8*)(xb + (wv + 8) * 32 + quad * 8);
  }

  for (int t = 0; t < TTOT; ++t) {
    const int p = t & 1;
    const ushort* __restrict__ hsrc = hbuf + p * (BSZ * HDIM);
    ushort* __restrict__ hdst = hbuf + (p ^ 1) * (BSZ * HDIM);

    // ---- h loads via IF (compiler schedules the waits before first use) ----
    const ushort* hb = hsrc + (long)(m0 + l15) * HDIM + wv * 32 + quad * 8;
    short8 ah0 = ld_h16(hb);
    short8 ah1 = ld_h16(hb + 256);
    short8 ah2 = ld_h16(hb + 512);
    short8 ah3 = ld_h16(hb + 768);

    f32x4 acc[NT];
    #pragma unroll
    for (int nt = 0; nt < NT; ++nt)
      #pragma unroll
      for (int r = 0; r < 4; ++r) acc[nt][r] = 0.0f;

    if (t < ILEN) {     // x projection overlaps h-load latency
      #pragma unroll
      for (int nt = 0; nt < NT; ++nt)
        acc[nt] = __builtin_amdgcn_mfma_f32_16x16x32_bf16(xa0, wfrag[0][nt], acc[nt], 0, 0, 0);
      #pragma unroll
      for (int nt = 0; nt < NT; ++nt)
        acc[nt] = __builtin_amdgcn_mfma_f32_16x16x32_bf16(xa1, wfrag[1][nt], acc[nt], 0, 0, 0);
    }
    #pragma unroll
    for (int nt = 0; nt < NT; ++nt)
      acc[nt] = __builtin_amdgcn_mfma_f32_16x16x32_bf16(ah0, wfrag[2][nt], acc[nt], 0, 0, 0);
    #pragma unroll
    for (int nt = 0; nt < NT; ++nt)
      acc[nt] = __builtin_amdgcn_mfma_f32_16x16x32_bf16(ah1, wfrag[3][nt], acc[nt], 0, 0, 0);
    #pragma unroll
    for (int nt = 0; nt < NT; ++nt)
      acc[nt] = __builtin_amdgcn_mfma_f32_16x16x32_bf16(ah2, wfrag[4][nt], acc[nt], 0, 0, 0);
    #pragma unroll
    for (int nt = 0; nt < NT; ++nt)
      acc[nt] = __builtin_amdgcn_mfma_f32_16x16x32_bf16(ah3, wfrag[5][nt], acc[nt], 0, 0, 0);

    // ---- partials to LDS, [w][m][n] (writes 2-way = free at PQ=76) ----
    #pragma unroll
    for (int nt = 0; nt < NT; ++nt)
      #pragma unroll
      for (int r = 0; r < 4; ++r)
        part[(wv * 16 + quad * 4 + r) * PQ + nt * 16 + l15] = acc[nt][r];
    __syncthreads();

    // ---- reduce 8 partials, LSTM cell (threads 0..255) ----
    if (tid < 256) {
      float gi = bi, gf = bf_, gg = bg, go = bo;
      #pragma unroll
      for (int w = 0; w < 8; ++w) {
        const float* pw = part + (w * 16 + em) * PQ;
        gi += pw[0 * 16 + uu];
        gf += pw[1 * 16 + uu];
        gg += pw[2 * 16 + uu];
        go += pw[3 * 16 + uu];
      }
      const float si = fast_sigmoid(gi);
      const float sf = fast_sigmoid(gf);
      const float tg = fast_tanh(gg);
      const float so = fast_sigmoid(go);
      cst = sf * cst + si * tg;
      const float h = so * fast_tanh(cst);
      const ushort h16 = f2bf(h);
      st_h(hdst + (long)(m0 + em) * HDIM + j0u + uu, h16);   // through IF
      if (t >= ILEN)
        hs_bf[((long)(m0 + em) * TLEN + (t - ILEN)) * HDIM + j0u + uu] = h16;
    }

    // ---- prefetch x for t+1 (plain cached; independent of barrier) ----
    if (t + 1 < ILEN) {
      const ushort* xb = inp_bf + ((long)(m0 + l15) * ILEN + (t + 1)) * IDIM;
      xa0 = *(const short8*)(xb + wv * 32 + quad * 8);
      xa1 = *(const short8*)(xb + (wv + 8) * 32 + quad * 8);
    }

    // ---- fence-free per-group barrier through IF ----
    vm_drain();                              // own h store reached IF
    __syncthreads();                         // all threads' stores drained
    if (tid == 0) st_flag(fmine, t + 1);     // publish (monotonic, no ABA)
    if (wv == 0) {
      int* fp = fbase + lane * 32;           // lane i watches block i of group
      for (;;) {
        int v = ld_flag(fp);
        if (__all(v > t)) break;
      }
    }
    __syncthreads();
  }
}

// ---------------- classifier: sigmoid(hs @ clf_w^T + clf_b) ----------------
__global__ __launch_bounds__(256, 1) void clf_kernel(
    const ushort* __restrict__ hs_bf, const ushort* __restrict__ clfw_bf,
    const float* __restrict__ clf_b, float* __restrict__ out)
{
  const int tid = threadIdx.x;
  const int wv = tid >> 6, lane = tid & 63, l15 = lane & 15, quad = lane >> 4;
  const int m0 = blockIdx.x * 64 + wv * 16;   // rows = (b, tt) pairs, 4096 total

  f32x4 acc[8];
  #pragma unroll
  for (int nt = 0; nt < 8; ++nt)
    #pragma unroll
    for (int r = 0; r < 4; ++r) acc[nt][r] = 0.0f;

  for (int kc = 0; kc < HDIM / 32; ++kc) {
    const int k = kc * 32 + quad * 8;
    short8 a = *(const short8*)(hs_bf + (long)(m0 + l15) * HDIM + k);
    #pragma unroll
    for (int nt = 0; nt < 8; ++nt) {
      short8 b = *(const short8*)(clfw_bf + (long)(nt * 16 + l15) * HDIM + k);
      acc[nt] = __builtin_amdgcn_mfma_f32_16x16x32_bf16(a, b, acc[nt], 0, 0, 0);
    }
  }
  #pragma unroll
  for (int nt = 0; nt < 8; ++nt) {
    const int n = nt * 16 + l15;
    const float bn = clf_b[n];
    #pragma unroll
    for (int r = 0; r < 4; ++r) {
      const int m = m0 + quad * 4 + r;
      out[(long)m * ODIM + n] = fast_sigmoid(acc[nt][r] + bn);
    }
  }
}

// ---------------- launch ----------------
extern "C" void kernel_launch(void* const* d_in, const int* in_sizes, int n_in,
                              void* d_out, int out_size, void* d_ws, size_t ws_size,
                              hipStream_t stream) {
  const float* inp   = (const float*)d_in[0];
  // d_in[1] = tlen scalar (fixed = 64 for this problem)
  const float* w_ih  = (const float*)d_in[2];
  const float* w_hh  = (const float*)d_in[3];
  const float* bias  = (const float*)d_in[4];
  const float* clf_w = (const float*)d_in[5];
  const float* clf_b = (const float*)d_in[6];
  float* out = (float*)d_out;

  // ws layout (bytes): total ~38.3 MB
  char* ws = (char*)d_ws;
  ushort* inp_bf  = (ushort*)(ws + 0);          // 16,777,216
  ushort* clfw_bf = (ushort*)(ws + 16777216);   //    262,144
  ushort* wsw     = (ushort*)(ws + 17039360);   // 12,582,912 (swizzled weights)
  ushort* hbuf    = (ushort*)(ws + 29622272);   //    262,144 (double-buffered h)
  ushort* hs_bf   = (ushort*)(ws + 29884416);   //  8,388,608 (last-64-step h)
  int*    bar     = (int*)   (ws + 38273024);   //     32,768 (per-block flags)

  prep_kernel<<<4096, 256, 0, stream>>>(inp, clf_w, w_ih, w_hh,
                                        inp_bf, clfw_bf, wsw, hbuf, bar);
  lstm_kernel<<<NBLK, NTHR, 8 * 16 * PQ * 4, stream>>>(inp_bf, wsw, bias,
                                                       hbuf, hs_bf, bar);
  clf_kernel<<<64, 256, 0, stream>>>(hs_bf, clfw_bf, clf_b, out);
}

// Round 5
// 1392.654 us; speedup vs baseline: 3.2601x; 1.0951x over previous
//
#include <hip/hip_runtime.h>
#include <hip/hip_bf16.h>

// Problem constants (fixed by the reference)
#define BSZ  64
#define ILEN 256
#define TLEN 64
#define TTOT (ILEN + TLEN)   // 320
#define IDIM 512
#define HDIM 1024
#define ODIM 128

// Partition: 4 batch-groups x 16 rows; 64 blocks/group (256 blocks = 256 CUs,
// 1 block/CU => all co-resident). Block owns 16 hidden units -> 64 gate rows
// (NT=4), K=1536 split over 8 waves; weight frags PINNED in registers via
// inline-asm (asm-defined values are not rematerializable -> no per-step
// reload; round 4's VGPR_Count=80 proved the compiler was re-loading).
// Sync: fine-grained producer flags. Wave wv's hh K-slice needs h units from
// exactly 8 producer blocks; it polls only those at iteration start. h ring
// buffer depth 4. All h/flag traffic via relaxed SYSTEM-scope atomics
// (sc0 sc1 -> memory-side Infinity Cache, coherent, fence-free).
#define NBLK 256
#define NTHR 512
#define GRP  4
#define GBLK 64          // blocks per group
#define UPB  16          // hidden units per block
#define NT   4           // n-tiles (16 gate rows each)
#define PQ   76          // LDS partial pitch (floats)
#define HSLOT (BSZ * HDIM)

typedef __attribute__((ext_vector_type(8))) short short8;  // 8 x bf16
typedef __attribute__((ext_vector_type(4))) float f32x4;

__device__ inline ushort f2bf(float f) {            // RNE float->bf16
  unsigned u = __builtin_bit_cast(unsigned, f);
  u += 0x7fffu + ((u >> 16) & 1u);
  return (ushort)(u >> 16);
}

__device__ inline float fast_sigmoid(float x) {
  float e = __expf(-x);
  return 1.0f / (1.0f + e);
}
__device__ inline float fast_tanh(float x) {
  float e = __expf(2.0f * x);
  return 1.0f - 2.0f / (1.0f + e);
}

// ---- IF-coherent ops (compiler-known: waitcnts auto-inserted) ----
__device__ inline short8 ld_h16(const ushort* p) {   // 16B via 2x8B system loads
  unsigned long lo = __hip_atomic_load((const unsigned long*)p,
                                       __ATOMIC_RELAXED, __HIP_MEMORY_SCOPE_SYSTEM);
  unsigned long hi = __hip_atomic_load((const unsigned long*)(p + 4),
                                       __ATOMIC_RELAXED, __HIP_MEMORY_SCOPE_SYSTEM);
  union { unsigned long u[2]; short8 v; } c;
  c.u[0] = lo; c.u[1] = hi;
  return c.v;
}
__device__ inline void st_h(ushort* p, ushort v) {
  __hip_atomic_store(p, v, __ATOMIC_RELAXED, __HIP_MEMORY_SCOPE_SYSTEM);
}
__device__ inline int ld_flag(const int* p) {
  return __hip_atomic_load(p, __ATOMIC_RELAXED, __HIP_MEMORY_SCOPE_SYSTEM);
}
__device__ inline void st_flag(int* p, int v) {
  __hip_atomic_store(p, v, __ATOMIC_RELAXED, __HIP_MEMORY_SCOPE_SYSTEM);
}
__device__ inline void vm_drain() { asm volatile("s_waitcnt vmcnt(0)" ::: "memory"); }

// ---------------- prep: bf16 conversions, weight swizzle, zero h0/flags ----------------
// wsw fragment index f = (((gb*8 + wv)*6 + ci)*4 + nt)*64 + lane; 8 bf16 each.
__global__ void prep_kernel(const float* __restrict__ inp, const float* __restrict__ clfw,
                            const float* __restrict__ w_ih, const float* __restrict__ w_hh,
                            ushort* __restrict__ inp_bf, ushort* __restrict__ clfw_bf,
                            ushort* __restrict__ wsw,
                            ushort* __restrict__ hbuf, int* __restrict__ bar)
{
  const long np  = (long)gridDim.x * blockDim.x;
  const long tid = (long)blockIdx.x * blockDim.x + threadIdx.x;

  const float4* in4 = (const float4*)inp;
  ushort4* ob4 = (ushort4*)inp_bf;
  for (long i = tid; i < (long)BSZ * ILEN * IDIM / 4; i += np) {
    float4 v = in4[i];
    ushort4 o; o.x = f2bf(v.x); o.y = f2bf(v.y); o.z = f2bf(v.z); o.w = f2bf(v.w);
    ob4[i] = o;
  }
  const float4* cw4 = (const float4*)clfw;
  ushort4* cb4 = (ushort4*)clfw_bf;
  for (long i = tid; i < (long)ODIM * HDIM / 4; i += np) {
    float4 v = cw4[i];
    ushort4 o; o.x = f2bf(v.x); o.y = f2bf(v.y); o.z = f2bf(v.z); o.w = f2bf(v.w);
    cb4[i] = o;
  }
  // weight swizzle: 64gb x 8wv x 6ci x 4nt x 64lane fragments of 8
  for (long f = tid; f < 64L * 8 * 6 * 4 * 64; f += np) {
    const int lane = (int)(f & 63);
    const int nt   = (int)((f >> 6) & 3);
    const int ci   = (int)((f >> 8) % 6);
    const int gbwv = (int)(f / 1536);
    const int wv   = gbwv & 7;
    const int gb   = gbwv >> 3;
    const int l15  = lane & 15, quad = lane >> 4;
    const int nl   = nt * 16 + l15;
    const long grow = (long)(nl >> 4) * HDIM + gb * 16 + (nl & 15);
    const float* src;
    if (ci < 2) src = w_ih + grow * IDIM + (wv + 8 * ci) * 32 + quad * 8;
    else        src = w_hh + grow * HDIM + wv * 32 + (ci - 2) * 256 + quad * 8;
    ushort* dst = wsw + f * 8;
    #pragma unroll
    for (int j = 0; j < 8; ++j) dst[j] = f2bf(src[j]);
  }
  // zero all 4 h ring slots through the SAME (system/IF) path readers use
  for (long i = tid; i < (long)4 * HSLOT; i += np)
    st_h(hbuf + i, 0);
  for (long i = tid; i < NBLK * 32; i += np) st_flag(bar + (int)i, 0);
}

// ---------------- persistent LSTM kernel ----------------
// MFMA 16x16x32 bf16 layouts (validated rounds 1-4):
//   A frag: A[m = lane&15][k = (lane>>4)*8 + j]
//   B frag: rows W[n][k], n = lane&15, k = (lane>>4)*8 + j
//   C/D:    col(n) = lane&15, row(m) = (lane>>4)*4 + reg
__global__ __launch_bounds__(NTHR, 2) void lstm_kernel(
    const ushort* __restrict__ inp_bf, const ushort* __restrict__ wsw,
    const float* __restrict__ bias,
    ushort* __restrict__ hbuf, ushort* __restrict__ hs_bf,
    int* __restrict__ flags)
{
  extern __shared__ float part[];   // [8 waves][16 m][PQ]

  const int tid  = threadIdx.x;
  const int wv   = tid >> 6;        // wave 0..7 (K split 8 ways)
  const int lane = tid & 63;
  const int l15  = lane & 15;
  const int quad = lane >> 4;
  const int blk  = blockIdx.x;
  const int g    = blk >> 6;        // batch group 0..3
  const int gb   = blk & 63;        // block within group
  const int j0u  = gb * UPB;        // first hidden unit owned by this block
  const int m0   = g * 16;          // first batch row of this group

  // ---- load + PIN register-resident pre-swizzled bf16 weight fragments ----
  short8 wfrag[6][NT];
  {
    const ushort* wp = wsw + ((long)(gb * 8 + wv) * 6 * 4 * 64 + lane) * 8;
    #pragma unroll
    for (int ci = 0; ci < 6; ++ci)
      #pragma unroll
      for (int nt = 0; nt < NT; ++nt)
        wfrag[ci][nt] = *(const short8*)(wp + (long)(ci * 4 + nt) * 64 * 8);
  }
  // asm-defined values cannot be rematerialized from memory by the register
  // allocator -> forces true residency across the 320-step loop.
  #pragma unroll
  for (int ci = 0; ci < 6; ++ci)
    #pragma unroll
    for (int nt = 0; nt < NT; ++nt)
      asm volatile("" : "+v"(wfrag[ci][nt]));

  // ---- elementwise cell mapping: threads 0..255 own (batch em, unit uu) ----
  const int em = tid >> 4;          // 0..15 (valid when tid<256)
  const int uu = tid & 15;          // 0..15
  float bi = 0, bf_ = 0, bg = 0, bo = 0;
  if (tid < 256) {
    bi  = bias[0 * HDIM + j0u + uu];
    bf_ = bias[1 * HDIM + j0u + uu];
    bg  = bias[2 * HDIM + j0u + uu];
    bo  = bias[3 * HDIM + j0u + uu];
  }
  float cst = 0.0f;

  // ---- fine-grained sync setup ----
  // Wave wv's hh chunk c (k = wv*32 + c*256) is produced by blocks
  // gb_p = 2*wv + 16*c and +1. Lanes 0..7 watch those 8 producers; lanes
  // 8..63 watch our own flag (always satisfied).
  int* const fmine = flags + blk * 32;        // own flag (128B stride)
  const int prodgb = 2 * wv + 16 * ((lane >> 1) & 3) + (lane & 1);
  const int fidx   = (lane < 8) ? (g * GBLK + prodgb) : blk;
  const int* const myfp = flags + fidx * 32;

  // prefetch x fragments for t=0 (read-only, plain cached loads)
  short8 xa0, xa1;
  {
    const ushort* xb = inp_bf + (long)(m0 + l15) * ILEN * IDIM;
    xa0 = *(const short8*)(xb + wv * 32 + quad * 8);
    xa1 = *(const short8*)(xb + (wv + 8) * 32 + quad * 8);
  }

  for (int t = 0; t < TTOT; ++t) {
    const ushort* __restrict__ hsrc = hbuf + (t & 3) * HSLOT;
    ushort* __restrict__ hdst = hbuf + ((t + 1) & 3) * HSLOT;

    // ---- wave-level poll: h_t ready when this wave's producers flag >= t ----
    for (;;) {
      int v = ld_flag(myfp);
      if (__all(v >= t)) break;
    }

    // ---- h loads via IF for this wave's K slice ----
    const ushort* hb = hsrc + (long)(m0 + l15) * HDIM + wv * 32 + quad * 8;
    short8 ah0 = ld_h16(hb);
    short8 ah1 = ld_h16(hb + 256);
    short8 ah2 = ld_h16(hb + 512);
    short8 ah3 = ld_h16(hb + 768);

    f32x4 acc[NT];
    #pragma unroll
    for (int nt = 0; nt < NT; ++nt)
      #pragma unroll
      for (int r = 0; r < 4; ++r) acc[nt][r] = 0.0f;

    if (t < ILEN) {     // x projection overlaps h-load latency
      #pragma unroll
      for (int nt = 0; nt < NT; ++nt)
        acc[nt] = __builtin_amdgcn_mfma_f32_16x16x32_bf16(xa0, wfrag[0][nt], acc[nt], 0, 0, 0);
      #pragma unroll
      for (int nt = 0; nt < NT; ++nt)
        acc[nt] = __builtin_amdgcn_mfma_f32_16x16x32_bf16(xa1, wfrag[1][nt], acc[nt], 0, 0, 0);
    }
    #pragma unroll
    for (int nt = 0; nt < NT; ++nt)
      acc[nt] = __builtin_amdgcn_mfma_f32_16x16x32_bf16(ah0, wfrag[2][nt], acc[nt], 0, 0, 0);
    #pragma unroll
    for (int nt = 0; nt < NT; ++nt)
      acc[nt] = __builtin_amdgcn_mfma_f32_16x16x32_bf16(ah1, wfrag[3][nt], acc[nt], 0, 0, 0);
    #pragma unroll
    for (int nt = 0; nt < NT; ++nt)
      acc[nt] = __builtin_amdgcn_mfma_f32_16x16x32_bf16(ah2, wfrag[4][nt], acc[nt], 0, 0, 0);
    #pragma unroll
    for (int nt = 0; nt < NT; ++nt)
      acc[nt] = __builtin_amdgcn_mfma_f32_16x16x32_bf16(ah3, wfrag[5][nt], acc[nt], 0, 0, 0);

    // ---- partials to LDS, [w][m][n] (writes 2-way = free at PQ=76) ----
    #pragma unroll
    for (int nt = 0; nt < NT; ++nt)
      #pragma unroll
      for (int r = 0; r < 4; ++r)
        part[(wv * 16 + quad * 4 + r) * PQ + nt * 16 + l15] = acc[nt][r];
    __syncthreads();    // also implies: every wave passed its poll => all 64
                        // group flags >= t => safe to overwrite ring slot t+1

    // ---- reduce 8 partials, LSTM cell (threads 0..255) ----
    if (tid < 256) {
      float gi = bi, gf = bf_, gg = bg, go = bo;
      #pragma unroll
      for (int w = 0; w < 8; ++w) {
        const float* pw = part + (w * 16 + em) * PQ;
        gi += pw[0 * 16 + uu];
        gf += pw[1 * 16 + uu];
        gg += pw[2 * 16 + uu];
        go += pw[3 * 16 + uu];
      }
      const float si = fast_sigmoid(gi);
      const float sf = fast_sigmoid(gf);
      const float tg = fast_tanh(gg);
      const float so = fast_sigmoid(go);
      cst = sf * cst + si * tg;
      const float h = so * fast_tanh(cst);
      const ushort h16 = f2bf(h);
      st_h(hdst + (long)(m0 + em) * HDIM + j0u + uu, h16);   // through IF
      if (t >= ILEN)
        hs_bf[((long)(m0 + em) * TLEN + (t - ILEN)) * HDIM + j0u + uu] = h16;
    }

    // ---- publish: own h stores at IF before flag store ----
    vm_drain();                              // per-thread store drain
    __syncthreads();                         // all threads drained; LDS reusable
    if (tid == 0) st_flag(fmine, t + 1);     // monotonic, no ABA

    // ---- prefetch x for t+1 (plain cached; lands during next poll) ----
    if (t + 1 < ILEN) {
      const ushort* xb = inp_bf + ((long)(m0 + l15) * ILEN + (t + 1)) * IDIM;
      xa0 = *(const short8*)(xb + wv * 32 + quad * 8);
      xa1 = *(const short8*)(xb + (wv + 8) * 32 + quad * 8);
    }
  }
}

// ---------------- classifier: sigmoid(hs @ clf_w^T + clf_b) ----------------
__global__ __launch_bounds__(256, 1) void clf_kernel(
    const ushort* __restrict__ hs_bf, const ushort* __restrict__ clfw_bf,
    const float* __restrict__ clf_b, float* __restrict__ out)
{
  const int tid = threadIdx.x;
  const int wv = tid >> 6, lane = tid & 63, l15 = lane & 15, quad = lane >> 4;
  const int m0 = blockIdx.x * 64 + wv * 16;   // rows = (b, tt) pairs, 4096 total

  f32x4 acc[8];
  #pragma unroll
  for (int nt = 0; nt < 8; ++nt)
    #pragma unroll
    for (int r = 0; r < 4; ++r) acc[nt][r] = 0.0f;

  for (int kc = 0; kc < HDIM / 32; ++kc) {
    const int k = kc * 32 + quad * 8;
    short8 a = *(const short8*)(hs_bf + (long)(m0 + l15) * HDIM + k);
    #pragma unroll
    for (int nt = 0; nt < 8; ++nt) {
      short8 b = *(const short8*)(clfw_bf + (long)(nt * 16 + l15) * HDIM + k);
      acc[nt] = __builtin_amdgcn_mfma_f32_16x16x32_bf16(a, b, acc[nt], 0, 0, 0);
    }
  }
  #pragma unroll
  for (int nt = 0; nt < 8; ++nt) {
    const int n = nt * 16 + l15;
    const float bn = clf_b[n];
    #pragma unroll
    for (int r = 0; r < 4; ++r) {
      const int m = m0 + quad * 4 + r;
      out[(long)m * ODIM + n] = fast_sigmoid(acc[nt][r] + bn);
    }
  }
}

// ---------------- launch ----------------
extern "C" void kernel_launch(void* const* d_in, const int* in_sizes, int n_in,
                              void* d_out, int out_size, void* d_ws, size_t ws_size,
                              hipStream_t stream) {
  const float* inp   = (const float*)d_in[0];
  // d_in[1] = tlen scalar (fixed = 64 for this problem)
  const float* w_ih  = (const float*)d_in[2];
  const float* w_hh  = (const float*)d_in[3];
  const float* bias  = (const float*)d_in[4];
  const float* clf_w = (const float*)d_in[5];
  const float* clf_b = (const float*)d_in[6];
  float* out = (float*)d_out;

  // ws layout (bytes): total ~38.6 MB
  char* ws = (char*)d_ws;
  ushort* inp_bf  = (ushort*)(ws + 0);          // 16,777,216
  ushort* clfw_bf = (ushort*)(ws + 16777216);   //    262,144
  ushort* wsw     = (ushort*)(ws + 17039360);   // 12,582,912 (swizzled weights)
  ushort* hbuf    = (ushort*)(ws + 29622272);   //    524,288 (4-slot h ring)
  ushort* hs_bf   = (ushort*)(ws + 30146560);   //  8,388,608 (last-64-step h)
  int*    bar     = (int*)   (ws + 38535168);   //     32,768 (per-block flags)

  prep_kernel<<<4096, 256, 0, stream>>>(inp, clf_w, w_ih, w_hh,
                                        inp_bf, clfw_bf, wsw, hbuf, bar);
  lstm_kernel<<<NBLK, NTHR, 8 * 16 * PQ * 4, stream>>>(inp_bf, wsw, bias,
                                                       hbuf, hs_bf, bar);
  clf_kernel<<<64, 256, 0, stream>>>(hs_bf, clfw_bf, clf_b, out);
}